// Round 7
// baseline (258.599 us; speedup 1.0000x reference)
//
#include <hip/hip_runtime.h>
#include <hip/hip_bf16.h>
#include <stdint.h>

#define B_ 8
#define N_ 2048
#define F_ 64
#define FH_ 64
#define H_ 4
#define C_ (H_*FH_)
#define CHUNK 64
#define LOG2E 1.44269504088896340736f

typedef short short8 __attribute__((ext_vector_type(8)));   // 8 bf16 raw bits (4 VGPRs)
typedef float f32x4 __attribute__((ext_vector_type(4)));

// float -> bf16 raw bits (RNE)
__device__ __forceinline__ short f2bf(float f) {
    __hip_bfloat16 h = __float2bfloat16(f);
    return __builtin_bit_cast(short, h);
}

// async global->LDS DMA
__device__ __forceinline__ void async16(void* l, const void* g) {
    __builtin_amdgcn_global_load_lds((const __attribute__((address_space(1))) unsigned int*)g,
                                     (__attribute__((address_space(3))) unsigned int*)l, 16, 0, 0);
}

// ---------------- KF: fused [k1 feats+scores | kp mask-pack] (unchanged) ----------------
__global__ __launch_bounds__(256) void kf(const float* __restrict__ A,
                                          const float* __restrict__ X,
                                          const float* __restrict__ W,
                                          const float* __restrict__ a_self,
                                          const float* __restrict__ a_neigh,
                                          unsigned long long* __restrict__ Amask,
                                          __hip_bfloat16* __restrict__ featsT,
                                          float* __restrict__ ss,
                                          float* __restrict__ sn) {
    __shared__ float a_lds[2][FH_];
    __shared__ __hip_bfloat16 cw_lds[FH_ * 72];    // W^T (bf16) during MFMA, then C
    const int bx = blockIdx.x;
    const int tid = threadIdx.x;
    const int wave = tid >> 6, lane = tid & 63;

    if (bx >= 1024) {
        // ---------------- kp part ----------------
        const int R = (bx - 1024) * 4 + wave;      // global row 0..16383 (= b*N + i)
        const float* arow = A + (size_t)R * N_;
        unsigned long long* mrow = Amask + (size_t)R * (N_ / 64);
#pragma unroll
        for (int i = 0; i < 8; ++i) {              // 8 x 256 cols
            float a0 = arow[i * 256 + lane];
            float a1 = arow[i * 256 + 64 + lane];
            float a2 = arow[i * 256 + 128 + lane];
            float a3 = arow[i * 256 + 192 + lane];
            unsigned long long m0 = __ballot(a0 != 0.0f);
            unsigned long long m1 = __ballot(a1 != 0.0f);
            unsigned long long m2 = __ballot(a2 != 0.0f);
            unsigned long long m3 = __ballot(a3 != 0.0f);
            if (lane == 0) {
                mrow[i * 4 + 0] = m0; mrow[i * 4 + 1] = m1;
                mrow[i * 4 + 2] = m2; mrow[i * 4 + 3] = m3;
            }
        }
        return;
    }

    // ---------------- k1 part ----------------
    const int nb = bx & 31, h = (bx >> 5) & 3, b = bx >> 7;

    if (tid < 64)       a_lds[0][tid] = a_self[h * FH_ + tid];
    else if (tid < 128) a_lds[1][tid - 64] = a_neigh[h * FH_ + tid - 64];
    {   // stage W[h] transposed to bf16: cw_lds[o*72+f] = bf16(W[h][f][o])
        int f = tid >> 2, o0 = (tid & 3) * 16;
        const float* wsrc = W + ((size_t)(h * F_ + f)) * FH_ + o0;
#pragma unroll
        for (int k = 0; k < 16; ++k)
            cw_lds[(o0 + k) * 72 + f] = __float2bfloat16(wsrc[k]);
    }
    __syncthreads();

    const int m = lane & 15, q = lane >> 4;
    const int nl = wave * 16 + m;               // local column 0..63
    const int n = nb * 64 + nl;                 // B-frag column (node index)
    f32x4 acc[4] = {};
#pragma unroll
    for (int ks = 0; ks < 2; ++ks) {            // K = F = 64, two steps of 32
        const float* xp = X + ((size_t)(b * N_ + n)) * F_ + ks * 32 + q * 8;
        float4 x0 = *(const float4*)xp;
        float4 x1 = *(const float4*)(xp + 4);
        short8 bfrag;
        bfrag[0] = f2bf(x0.x); bfrag[1] = f2bf(x0.y);
        bfrag[2] = f2bf(x0.z); bfrag[3] = f2bf(x0.w);
        bfrag[4] = f2bf(x1.x); bfrag[5] = f2bf(x1.y);
        bfrag[6] = f2bf(x1.z); bfrag[7] = f2bf(x1.w);
#pragma unroll
        for (int ot = 0; ot < 4; ++ot) {
            short8 afrag = *(const short8*)(cw_lds + (ot * 16 + m) * 72 + ks * 32 + q * 8);
            acc[ot] = __builtin_amdgcn_mfma_f32_16x16x32_bf16(afrag, bfrag, acc[ot], 0, 0, 0);
        }
    }
    __syncthreads();    // all W reads done before C overwrites the buffer
    float ssv = 0.f, snv = 0.f;
#pragma unroll
    for (int ot = 0; ot < 4; ++ot) {
#pragma unroll
        for (int r = 0; r < 4; ++r) {
            int orow = ot * 16 + q * 4 + r;     // C: row=(lane>>4)*4+r, col=lane&15
            float v = acc[ot][r];
            cw_lds[orow * 72 + nl] = __float2bfloat16(v);
            ssv += v * a_lds[0][orow];
            snv += v * a_lds[1][orow];
        }
    }
    ssv += __shfl_xor(ssv, 16); ssv += __shfl_xor(ssv, 32);
    snv += __shfl_xor(snv, 16); snv += __shfl_xor(snv, 32);
    __syncthreads();
    {   // coalesced featsT store: thread t -> feature o = t>>2, 16-col chunk (t&3)
        int o = tid >> 2, c = (tid & 3) * 16;
        const __hip_bfloat16* src = cw_lds + o * 72 + c;
        __hip_bfloat16* dst = featsT + ((size_t)(b * H_ + h) * FH_ + o) * N_ + nb * 64 + c;
        *(uint4*)dst       = *(const uint4*)src;
        *(uint4*)(dst + 8) = *(const uint4*)(src + 8);
    }
    if (lane < 16) {
        size_t idx = ((size_t)(b * H_ + h)) * N_ + n;
        ss[idx] = ssv * LOG2E;
        sn[idx] = snv * LOG2E;
    }
}

// ---------------- K3: barrier-free column-partitioned softmax+PV (R19) ----------------
// R4/R5 counters: P-build VALU ~31 us (dominant), MFMA ~8 us; R3's 58 us = poor
// overlap (per-chunk barrier + 4x shared-fv LDS re-read serialize the pipes).
// Restructure: block = 64 rows; each WAVE owns a private 512-col range (8 chunks
// of 64). fv chunks are wave-private -> staged via global_load_lds into a private
// 8 KB LDS buffer, waited by the wave's OWN s_waitcnt vmcnt(0): NO block barriers
// in the main loop. One set of 8 ds_read_b128 feeds 40 MFMAs (4 row-groups share
// B-frags): LDS reads /4. P math, e-tables, mask test, XOR swizzle = R12-verbatim
// (numerics bit-identical). Epilogue: 4-barrier cross-wave reduction in LDS.
__global__ __launch_bounds__(256, 2) void k3_attn(const unsigned int* __restrict__ Amask,
                                                  const __hip_bfloat16* __restrict__ featsT,
                                                  const float* __restrict__ ss,
                                                  const float* __restrict__ sn,
                                                  const float* __restrict__ bias,
                                                  float* __restrict__ out) {
    // [e1 8K][e2 8K][fv 4x8K] ; reduction reuses [e2..fv] = 40 KB after the loop
    __shared__ char smem[49152];
    float* e1_lds = (float*)smem;
    float* e2_lds = (float*)(smem + 8192);
    __hip_bfloat16* fv_all = (__hip_bfloat16*)(smem + 16384);

    const int bx = blockIdx.x;
    const int tile = bx & 31, h = (bx >> 5) & 3, b = bx >> 7;
    const int tid = threadIdx.x, wave = tid >> 6, lane = tid & 63;
    const int m = lane & 15, q = lane >> 4;
    const int rowtile = tile * 64;
    const int colbase = wave * 512;                 // this wave's private columns
    __hip_bfloat16* fvw = fv_all + wave * 4096;     // private 8 KB buffer

    {   // e-tables: 2^sn_j and 2^(0.2 sn_j), 512 float4 slots
        const float4* snrow = (const float4*)(sn + ((size_t)(b * H_ + h)) * N_);
        float4* e1v = (float4*)e1_lds;
        float4* e2v = (float4*)e2_lds;
#pragma unroll
        for (int i = 0; i < 2; ++i) {
            int idx = tid + i * 256;
            float4 v = snrow[idx];
            float4 u1, u2;
            u1.x = exp2f(v.x); u1.y = exp2f(v.y); u1.z = exp2f(v.z); u1.w = exp2f(v.w);
            u2.x = exp2f(0.2f * v.x); u2.y = exp2f(0.2f * v.y);
            u2.z = exp2f(0.2f * v.z); u2.w = exp2f(0.2f * v.w);
            e1v[idx] = u1; e2v[idx] = u2;
        }
    }
    // per-row self terms for the 4 row-groups (rows shared by all waves)
    const float* ssrow = ss + ((size_t)(b * H_ + h)) * N_ + rowtile;
    float e1i[4], e2i[4];
#pragma unroll
    for (int rg = 0; rg < 4; ++rg) {
        float s_ = ssrow[rg * 16 + m];
        e1i[rg] = exp2f(s_); e2i[rg] = exp2f(0.2f * s_);
    }

    const __hip_bfloat16* fhead = featsT + ((size_t)(b * H_ + h)) * FH_ * N_;
    // per-thread mask base: row rowtile+m (+16 per rg = +1024 dwords), this wave's cols
    const unsigned int* mrow = Amask + ((size_t)(b * N_) + rowtile + m) * (N_ / 32) + (colbase >> 5);

    // stage chunk c of this wave's columns into the private buffer (R12 swizzle)
    auto stage = [&](int c) {
        const int cb = colbase + c * CHUNK;
#pragma unroll
        for (int i = 0; i < 8; ++i) {              // 512 16B-units, 64/call
            int unit = i * 64 + lane;
            int o = unit >> 3, v = unit & 7;
            int u = v ^ (o & 7);                   // XOR swizzle
            async16(fvw + (size_t)(i * 64) * 8, fhead + (size_t)o * N_ + cb + u * 8);
        }
    };

    uint2 mk[4];
#pragma unroll
    for (int rg = 0; rg < 4; ++rg) mk[rg] = *(const uint2*)(mrow + rg * 1024);
    stage(0);
    __syncthreads();    // e-tables ready; drains vmcnt -> chunk 0 + masks landed

    f32x4 acc[4][4] = {};       // [rowgroup][ct]
    f32x4 accl[4] = {};         // [rowgroup] row-sums
    short8 ones;
#pragma unroll
    for (int t = 0; t < 8; ++t) ones[t] = (short)0x3F80;   // bf16 1.0

    for (int c = 0; c < 8; ++c) {
        // fv B-frags from private buffer (chunk c landed)
        short8 fA[4], fB[4];
#pragma unroll
        for (int ct = 0; ct < 4; ++ct) {
            int o = ct * 16 + m;
            fA[ct] = *(const short8*)(fvw + ((o << 3) + (q ^ (o & 7))) * 8);
            fB[ct] = *(const short8*)(fvw + ((o << 3) + ((4 + q) ^ (o & 7))) * 8);
        }
        // retire LDS reads (frags in VGPRs) -> buffer reusable
        asm volatile("s_waitcnt lgkmcnt(0)" ::: "memory");
        __builtin_amdgcn_sched_barrier(0);
        if (c + 1 < 8) stage(c + 1);               // DMA next chunk into same buffer
        // mask prefetch for next chunk
        uint2 mkn[4];
        if (c + 1 < 8) {
#pragma unroll
            for (int rg = 0; rg < 4; ++rg) mkn[rg] = *(const uint2*)(mrow + rg * 1024 + (c + 1) * 2);
        }

        // e-tables for this chunk's cols (shared across row-groups)
        const int cb = colbase + c * CHUNK;
        float4 a10 = *(const float4*)(e1_lds + cb + q * 8);
        float4 a11 = *(const float4*)(e1_lds + cb + q * 8 + 4);
        float4 b10 = *(const float4*)(e1_lds + cb + 32 + q * 8);
        float4 b11 = *(const float4*)(e1_lds + cb + 32 + q * 8 + 4);
        float4 a20 = *(const float4*)(e2_lds + cb + q * 8);
        float4 a21 = *(const float4*)(e2_lds + cb + q * 8 + 4);
        float4 b20 = *(const float4*)(e2_lds + cb + 32 + q * 8);
        float4 b21 = *(const float4*)(e2_lds + cb + 32 + q * 8 + 4);
        float e1A[8] = {a10.x, a10.y, a10.z, a10.w, a11.x, a11.y, a11.z, a11.w};
        float e1B[8] = {b10.x, b10.y, b10.z, b10.w, b11.x, b11.y, b11.z, b11.w};
        float e2A[8] = {a20.x, a20.y, a20.z, a20.w, a21.x, a21.y, a21.z, a21.w};
        float e2B[8] = {b20.x, b20.y, b20.z, b20.w, b21.x, b21.y, b21.z, b21.w};

        // P-build + MFMA per row-group (P frags short-lived: 8 VGPRs at a time)
#pragma unroll
        for (int rg = 0; rg < 4; ++rg) {
            short8 pA, pB;
            unsigned int mA = mk[rg].x, mB = mk[rg].y;
#pragma unroll
            for (int t = 0; t < 8; ++t) {
                float vA = fmaxf(e1i[rg] * e1A[t], e2i[rg] * e2A[t]);
                float vB = fmaxf(e1i[rg] * e1B[t], e2i[rg] * e2B[t]);
                const int bit = q * 8 + t;
                pA[t] = (mA >> bit) & 1 ? f2bf(vA) : (short)0;
                pB[t] = (mB >> bit) & 1 ? f2bf(vB) : (short)0;
            }
#pragma unroll
            for (int ct = 0; ct < 4; ++ct) {
                acc[rg][ct] = __builtin_amdgcn_mfma_f32_16x16x32_bf16(pA, fA[ct], acc[rg][ct], 0, 0, 0);
                acc[rg][ct] = __builtin_amdgcn_mfma_f32_16x16x32_bf16(pB, fB[ct], acc[rg][ct], 0, 0, 0);
            }
            accl[rg] = __builtin_amdgcn_mfma_f32_16x16x32_bf16(pA, ones, accl[rg], 0, 0, 0);
            accl[rg] = __builtin_amdgcn_mfma_f32_16x16x32_bf16(pB, ones, accl[rg], 0, 0, 0);
        }

        if (c + 1 < 8) {    // next chunk's DMA (+ masks) landed before next iter reads
            asm volatile("s_waitcnt vmcnt(0)" ::: "memory");
            __builtin_amdgcn_sched_barrier(0);
#pragma unroll
            for (int rg = 0; rg < 4; ++rg) mk[rg] = mkn[rg];
        }
    }

    // ---- cross-wave reduction: sum partial acc/accl over the 4 col-ranges ----
    // red = [e2|fv] region, 2 slots x 5120 floats (20 KB each); lane-matched.
    float* red = (float*)(smem + 8192);
    __syncthreads();    // all waves done: e-tables + fv buffers dead
    if (wave >= 2) {    // waves 2,3 -> slots 0,1
        float* base = red + (wave - 2) * 5120 + lane * 80;
#pragma unroll
        for (int rg = 0; rg < 4; ++rg) {
#pragma unroll
            for (int ct = 0; ct < 4; ++ct) *(f32x4*)(base + (rg * 4 + ct) * 4) = acc[rg][ct];
            *(f32x4*)(base + 64 + rg * 4) = accl[rg];
        }
    }
    __syncthreads();
    if (wave < 2) {     // waves 0,1 absorb slots 0,1
        const float* base = red + wave * 5120 + lane * 80;
#pragma unroll
        for (int rg = 0; rg < 4; ++rg) {
#pragma unroll
            for (int ct = 0; ct < 4; ++ct) acc[rg][ct] += *(const f32x4*)(base + (rg * 4 + ct) * 4);
            accl[rg] += *(const f32x4*)(base + 64 + rg * 4);
        }
    }
    __syncthreads();
    if (wave == 1) {    // wave 1 -> slot 0
        float* base = red + lane * 80;
#pragma unroll
        for (int rg = 0; rg < 4; ++rg) {
#pragma unroll
            for (int ct = 0; ct < 4; ++ct) *(f32x4*)(base + (rg * 4 + ct) * 4) = acc[rg][ct];
            *(f32x4*)(base + 64 + rg * 4) = accl[rg];
        }
    }
    __syncthreads();
    if (wave == 0) {    // wave 0: final sum, normalize, bias, relu, store
        const float* base = red + lane * 80;
        float bc[4];
#pragma unroll
        for (int ct = 0; ct < 4; ++ct) bc[ct] = bias[h * FH_ + ct * 16 + m];
#pragma unroll
        for (int rg = 0; rg < 4; ++rg) {
#pragma unroll
            for (int ct = 0; ct < 4; ++ct) acc[rg][ct] += *(const f32x4*)(base + (rg * 4 + ct) * 4);
            accl[rg] += *(const f32x4*)(base + 64 + rg * 4);
#pragma unroll
            for (int r = 0; r < 4; ++r) {
                float inv = 1.0f / accl[rg][r];     // row sum (cols identical)
                int gr = rowtile + rg * 16 + q * 4 + r;
#pragma unroll
                for (int ct = 0; ct < 4; ++ct) {
                    float v = acc[rg][ct][r] * inv + bc[ct];
                    out[((size_t)(b * N_) + gr) * C_ + h * FH_ + ct * 16 + m] = fmaxf(v, 0.0f);
                }
            }
        }
    }
}

extern "C" void kernel_launch(void* const* d_in, const int* in_sizes, int n_in,
                              void* d_out, int out_size, void* d_ws, size_t ws_size,
                              hipStream_t stream) {
    const float* X       = (const float*)d_in[0];
    const float* A       = (const float*)d_in[1];
    const float* W       = (const float*)d_in[2];
    const float* bias    = (const float*)d_in[3];
    const float* a_self  = (const float*)d_in[4];
    const float* a_neigh = (const float*)d_in[5];
    float* out = (float*)d_out;   // reference output dtype is float32

    char* ws = (char*)d_ws;
    __hip_bfloat16* featsT = (__hip_bfloat16*)(ws);             // 8 MB   [B][H][FH][N]
    float* ss              = (float*)(ws + 8421376);            // 256 KB [B][H][N]
    float* sn              = (float*)(ws + 8683520);            // 256 KB [B][H][N]
    unsigned long long* Am = (unsigned long long*)(ws + 8945664); // 4 MB bitmask

    kf      <<<5120, 256, 0, stream>>>(A, X, W, a_self, a_neigh, Am, featsT, ss, sn);
    k3_attn <<<1024, 256, 0, stream>>>((const unsigned int*)Am, featsT, ss, sn, bias, out);
}

// Round 8
// 253.928 us; speedup vs baseline: 1.0184x; 1.0184x over previous
//
#include <hip/hip_runtime.h>
#include <hip/hip_bf16.h>
#include <stdint.h>

#define B_ 8
#define N_ 2048
#define F_ 64
#define FH_ 64
#define H_ 4
#define C_ (H_*FH_)
#define CHUNK 64
#define NCHUNK (N_/CHUNK)
#define LOG2E 1.44269504088896340736f

typedef short short8 __attribute__((ext_vector_type(8)));   // 8 bf16 raw bits (4 VGPRs)
typedef float f32x4 __attribute__((ext_vector_type(4)));
typedef float f32x2 __attribute__((ext_vector_type(2)));

// float -> bf16 raw bits (RNE)
__device__ __forceinline__ short f2bf(float f) {
    __hip_bfloat16 h = __float2bfloat16(f);
    return __builtin_bit_cast(short, h);
}

// async global->LDS DMA
__device__ __forceinline__ void async16(void* l, const void* g) {
    __builtin_amdgcn_global_load_lds((const __attribute__((address_space(1))) unsigned int*)g,
                                     (__attribute__((address_space(3))) unsigned int*)l, 16, 0, 0);
}

// ---------------- KF: fused [k1 feats+scores | kp mask-pack] (unchanged) ----------------
// Blocks [0,1024): k1 (featsT + ss/sn). Blocks [1024,5120): kp (A -> 1-bit mask).
// Fusing overlaps the ~19 us HBM-bound A read with the k1 MFMA work.
__global__ __launch_bounds__(256) void kf(const float* __restrict__ A,
                                          const float* __restrict__ X,
                                          const float* __restrict__ W,
                                          const float* __restrict__ a_self,
                                          const float* __restrict__ a_neigh,
                                          unsigned long long* __restrict__ Amask,
                                          __hip_bfloat16* __restrict__ featsT,
                                          float* __restrict__ ss,
                                          float* __restrict__ sn) {
    __shared__ float a_lds[2][FH_];
    __shared__ __hip_bfloat16 cw_lds[FH_ * 72];    // W^T (bf16) during MFMA, then C
    const int bx = blockIdx.x;
    const int tid = threadIdx.x;
    const int wave = tid >> 6, lane = tid & 63;

    if (bx >= 1024) {
        // ---------------- kp part ----------------
        const int R = (bx - 1024) * 4 + wave;      // global row 0..16383 (= b*N + i)
        const float* arow = A + (size_t)R * N_;
        unsigned long long* mrow = Amask + (size_t)R * (N_ / 64);
#pragma unroll
        for (int i = 0; i < 8; ++i) {              // 8 x 256 cols
            float a0 = arow[i * 256 + lane];
            float a1 = arow[i * 256 + 64 + lane];
            float a2 = arow[i * 256 + 128 + lane];
            float a3 = arow[i * 256 + 192 + lane];
            unsigned long long m0 = __ballot(a0 != 0.0f);
            unsigned long long m1 = __ballot(a1 != 0.0f);
            unsigned long long m2 = __ballot(a2 != 0.0f);
            unsigned long long m3 = __ballot(a3 != 0.0f);
            if (lane == 0) {
                mrow[i * 4 + 0] = m0; mrow[i * 4 + 1] = m1;
                mrow[i * 4 + 2] = m2; mrow[i * 4 + 3] = m3;
            }
        }
        return;
    }

    // ---------------- k1 part ----------------
    const int nb = bx & 31, h = (bx >> 5) & 3, b = bx >> 7;

    if (tid < 64)       a_lds[0][tid] = a_self[h * FH_ + tid];
    else if (tid < 128) a_lds[1][tid - 64] = a_neigh[h * FH_ + tid - 64];
    {   // stage W[h] transposed to bf16: cw_lds[o*72+f] = bf16(W[h][f][o])
        int f = tid >> 2, o0 = (tid & 3) * 16;
        const float* wsrc = W + ((size_t)(h * F_ + f)) * FH_ + o0;
#pragma unroll
        for (int k = 0; k < 16; ++k)
            cw_lds[(o0 + k) * 72 + f] = __float2bfloat16(wsrc[k]);
    }
    __syncthreads();

    const int m = lane & 15, q = lane >> 4;
    const int nl = wave * 16 + m;               // local column 0..63
    const int n = nb * 64 + nl;                 // B-frag column (node index)
    f32x4 acc[4] = {};
#pragma unroll
    for (int ks = 0; ks < 2; ++ks) {            // K = F = 64, two steps of 32
        const float* xp = X + ((size_t)(b * N_ + n)) * F_ + ks * 32 + q * 8;
        float4 x0 = *(const float4*)xp;
        float4 x1 = *(const float4*)(xp + 4);
        short8 bfrag;
        bfrag[0] = f2bf(x0.x); bfrag[1] = f2bf(x0.y);
        bfrag[2] = f2bf(x0.z); bfrag[3] = f2bf(x0.w);
        bfrag[4] = f2bf(x1.x); bfrag[5] = f2bf(x1.y);
        bfrag[6] = f2bf(x1.z); bfrag[7] = f2bf(x1.w);
#pragma unroll
        for (int ot = 0; ot < 4; ++ot) {
            short8 afrag = *(const short8*)(cw_lds + (ot * 16 + m) * 72 + ks * 32 + q * 8);
            acc[ot] = __builtin_amdgcn_mfma_f32_16x16x32_bf16(afrag, bfrag, acc[ot], 0, 0, 0);
        }
    }
    __syncthreads();    // all W reads done before C overwrites the buffer
    float ssv = 0.f, snv = 0.f;
#pragma unroll
    for (int ot = 0; ot < 4; ++ot) {
#pragma unroll
        for (int r = 0; r < 4; ++r) {
            int orow = ot * 16 + q * 4 + r;     // C: row=(lane>>4)*4+r, col=lane&15
            float v = acc[ot][r];
            cw_lds[orow * 72 + nl] = __float2bfloat16(v);
            ssv += v * a_lds[0][orow];
            snv += v * a_lds[1][orow];
        }
    }
    ssv += __shfl_xor(ssv, 16); ssv += __shfl_xor(ssv, 32);
    snv += __shfl_xor(snv, 16); snv += __shfl_xor(snv, 32);
    __syncthreads();
    {   // coalesced featsT store: thread t -> feature o = t>>2, 16-col chunk (t&3)
        int o = tid >> 2, c = (tid & 3) * 16;
        const __hip_bfloat16* src = cw_lds + o * 72 + c;
        __hip_bfloat16* dst = featsT + ((size_t)(b * H_ + h) * FH_ + o) * N_ + nb * 64 + c;
        *(uint4*)dst       = *(const uint4*)src;
        *(uint4*)(dst + 8) = *(const uint4*)(src + 8);
    }
    if (lane < 16) {
        size_t idx = ((size_t)(b * H_ + h)) * N_ + n;
        ss[idx] = ssv * LOG2E;
        sn[idx] = snv * LOG2E;
    }
}

// ---------------- K3: DMA-pipelined fused softmax+PV, pk-mul e-table (R20) ----------------
// Base = R3/R15 verbatim (best verified 249.5: LDS-DMA fv staging, pipelined-P,
// register masks, per-chunk barrier, 4 blocks/CU). R19's barrier-free variant
// regressed (80 acc VGPRs -> 8 waves/CU; occupancy rule confirmed twice).
// ONE change: e1/e2 tables fused into an INTERLEAVED pair table
// et[j]=(2^sn_j, 2^(0.2 sn_j)); P-build computes both products with a single
// f32x2 multiply (v_pk_mul_f32 on CDNA4) -> per element pk_mul+max instead of
// mul+mul+max (~15-20%% off the dominant ~31 us P-build VALU). Same LDS bytes,
// same ds_read count, bit-identical math (IEEE mul/max; absmax must stay equal).
__global__ __launch_bounds__(256, 4) void k3_attn(const unsigned int* __restrict__ Amask,
                                                  const __hip_bfloat16* __restrict__ featsT,
                                                  const float* __restrict__ ss,
                                                  const float* __restrict__ sn,
                                                  const float* __restrict__ bias,
                                                  float* __restrict__ out) {
    __shared__ __hip_bfloat16 fv_lds[2][64 * CHUNK];   // 2 x 8 KB, swizzled
    __shared__ float et_lds[N_ * 2];                   // 16 KB: (2^sn_j, 2^(0.2 sn_j)) pairs

    const int tile = blockIdx.x, h = blockIdx.y, b = blockIdx.z;
    const int tid = threadIdx.x, wave = tid >> 6, lane = tid & 63;
    const int m = lane & 15, q = lane >> 4;
    const int rowtile = tile * 64;

    {   // interleaved e-table: 512 sn-float4 slots, 2 per thread -> 2 float4 writes each
        const float4* snrow = (const float4*)(sn + ((size_t)(b * H_ + h)) * N_);
        float4* etv = (float4*)et_lds;
#pragma unroll
        for (int i = 0; i < 2; ++i) {
            int idx = tid + i * 256;        // covers cols 4*idx .. 4*idx+3
            float4 v = snrow[idx];
            float4 w0, w1;
            w0.x = exp2f(v.x); w0.y = exp2f(0.2f * v.x);
            w0.z = exp2f(v.y); w0.w = exp2f(0.2f * v.y);
            w1.x = exp2f(v.z); w1.y = exp2f(0.2f * v.z);
            w1.z = exp2f(v.w); w1.w = exp2f(0.2f * v.w);
            etv[idx * 2]     = w0;
            etv[idx * 2 + 1] = w1;
        }
    }
    const float ssi = ss[((size_t)(b * H_ + h)) * N_ + rowtile + wave * 16 + m];
    const f32x2 ei2 = {exp2f(ssi), exp2f(0.2f * ssi)};   // (e1i, e2i) pair

    const __hip_bfloat16* fhead = featsT + ((size_t)(b * H_ + h)) * FH_ * N_;
    // per-thread mask row pointer: row = rowtile + wave*16 + m, 2 dwords per chunk
    const unsigned int* mrow = Amask + ((size_t)(b * N_) + rowtile + wave * 16 + m) * (N_ / 32);

    // stage fv chunk c into buffer bufi (wave-uniform LDS base + lane*size per HW contract)
    auto stage = [&](int c, int bufi) {
        const int cb = c * CHUNK;
#pragma unroll
        for (int i = 0; i < 2; ++i) {           // fv: 64 feats x 64 cols, 512 16B-units
            int base_unit = i * 256 + wave * 64;
            int unit = base_unit + lane;
            int o = unit >> 3, v = unit & 7;
            int u = v ^ (o & 7);                // XOR swizzle (compute-side conflict-free)
            async16(&fv_lds[bufi][base_unit * 8], fhead + (size_t)o * N_ + cb + u * 8);
        }
    };

    // build P (pA, pB) for chunk c from the interleaved table + mask registers
    auto buildP = [&](int c, unsigned int mA, unsigned int mB, short8& pA, short8& pB) {
        const int cg = c * CHUNK;
        // chain A cols cg+q*8..+7 and chain B +32: pair data = 64 B each = 4 float4s
        const float4* etv = (const float4*)et_lds;
        const int ia = (cg >> 1) + q * 4;           // float4 index: 2 cols per float4
        float4 a0 = etv[ia + 0], a1 = etv[ia + 1], a2 = etv[ia + 2], a3 = etv[ia + 3];
        float4 b0 = etv[ia + 16], b1 = etv[ia + 17], b2 = etv[ia + 18], b3 = etv[ia + 19];
        f32x2 eA[8] = {{a0.x, a0.y}, {a0.z, a0.w}, {a1.x, a1.y}, {a1.z, a1.w},
                       {a2.x, a2.y}, {a2.z, a2.w}, {a3.x, a3.y}, {a3.z, a3.w}};
        f32x2 eB[8] = {{b0.x, b0.y}, {b0.z, b0.w}, {b1.x, b1.y}, {b1.z, b1.w},
                       {b2.x, b2.y}, {b2.z, b2.w}, {b3.x, b3.y}, {b3.z, b3.w}};
#pragma unroll
        for (int t = 0; t < 8; ++t) {
            // exp2(leaky(si+sj)) = max(e1i*e1j, e2i*e2j) via one packed mul + max
            f32x2 prA = ei2 * eA[t];
            f32x2 prB = ei2 * eB[t];
            float vA = fmaxf(prA.x, prA.y);
            float vB = fmaxf(prB.x, prB.y);
            const int bit = q * 8 + t;
            pA[t] = (mA >> bit) & 1 ? f2bf(vA) : (short)0;
            pB[t] = (mB >> bit) & 1 ? f2bf(vB) : (short)0;
        }
    };

    // early mask loads (latency hidden under e-table exp2 work)
    uint2 mk_use = *(const uint2*)(mrow + 0);   // chunk 0
    uint2 mk_a   = *(const uint2*)(mrow + 2);   // chunk 1

    stage(0, 0);
    __syncthreads();    // drains DMA (vmcnt -> masks also landed) + e-table LDS writes

    f32x4 acc[2][4] = {};       // [chain][ct]
    f32x4 accl[2] = {};
    short8 ones;
#pragma unroll
    for (int t = 0; t < 8; ++t) ones[t] = (short)0x3F80;   // bf16 1.0

    short8 pA, pB;
    buildP(0, mk_use.x, mk_use.y, pA, pB);

    for (int c = 0; c < NCHUNK; ++c) {
        const int cur = c & 1;
        if (c + 1 < NCHUNK) stage(c + 1, cur ^ 1);
        uint2 mk_b = mk_a;
        if (c + 2 < NCHUNK) mk_b = *(const uint2*)(mrow + (c + 2) * 2);

        // fv fragments: chain A = col-units 0..3 (uA=q), chain B = units 4..7
        short8 fA[4], fB[4];
#pragma unroll
        for (int ct = 0; ct < 4; ++ct) {
            int o = ct * 16 + m;
            fA[ct] = *(const short8*)(fv_lds[cur] + ((o << 3) + (q ^ (o & 7))) * 8);
            fB[ct] = *(const short8*)(fv_lds[cur] + ((o << 3) + ((4 + q) ^ (o & 7))) * 8);
        }
#pragma unroll
        for (int ct = 0; ct < 4; ++ct) {
            acc[0][ct] = __builtin_amdgcn_mfma_f32_16x16x32_bf16(pA, fA[ct], acc[0][ct], 0, 0, 0);
            acc[1][ct] = __builtin_amdgcn_mfma_f32_16x16x32_bf16(pB, fB[ct], acc[1][ct], 0, 0, 0);
        }
        accl[0] = __builtin_amdgcn_mfma_f32_16x16x32_bf16(pA, ones, accl[0], 0, 0, 0);
        accl[1] = __builtin_amdgcn_mfma_f32_16x16x32_bf16(pB, ones, accl[1], 0, 0, 0);

        // build P for next chunk while this chunk's DMA is in flight (in-place:
        // MFMAs above have consumed the old pA/pB)
        if (c + 1 < NCHUNK) buildP(c + 1, mk_a.x, mk_a.y, pA, pB);
        mk_a = mk_b;

        __syncthreads();    // drain next-chunk DMA; release cur buffer
    }

    float bc[4];
#pragma unroll
    for (int ct = 0; ct < 4; ++ct) bc[ct] = bias[h * FH_ + ct * 16 + m];

#pragma unroll
    for (int r = 0; r < 4; ++r) {
        float inv = 1.0f / (accl[0][r] + accl[1][r]);   // row sum (all cols identical)
        int gr = rowtile + wave * 16 + q * 4 + r;
#pragma unroll
        for (int ct = 0; ct < 4; ++ct) {
            float v = (acc[0][ct][r] + acc[1][ct][r]) * inv + bc[ct];
            out[((size_t)(b * N_) + gr) * C_ + h * FH_ + ct * 16 + m] = fmaxf(v, 0.0f);
        }
    }
}

extern "C" void kernel_launch(void* const* d_in, const int* in_sizes, int n_in,
                              void* d_out, int out_size, void* d_ws, size_t ws_size,
                              hipStream_t stream) {
    const float* X       = (const float*)d_in[0];
    const float* A       = (const float*)d_in[1];
    const float* W       = (const float*)d_in[2];
    const float* bias    = (const float*)d_in[3];
    const float* a_self  = (const float*)d_in[4];
    const float* a_neigh = (const float*)d_in[5];
    float* out = (float*)d_out;   // reference output dtype is float32

    char* ws = (char*)d_ws;
    __hip_bfloat16* featsT = (__hip_bfloat16*)(ws);             // 8 MB   [B][H][FH][N]
    float* ss              = (float*)(ws + 8421376);            // 256 KB [B][H][N]
    float* sn              = (float*)(ws + 8683520);            // 256 KB [B][H][N]
    unsigned long long* Am = (unsigned long long*)(ws + 8945664); // 4 MB bitmask

    kf      <<<5120, 256, 0, stream>>>(A, X, W, a_self, a_neigh, Am, featsT, ss, sn);
    k3_attn <<<dim3(N_ / 64, H_, B_), 256, 0, stream>>>((const unsigned int*)Am, featsT, ss, sn, bias, out);
}

// Round 9
// 252.532 us; speedup vs baseline: 1.0240x; 1.0055x over previous
//
#include <hip/hip_runtime.h>
#include <hip/hip_bf16.h>
#include <stdint.h>

#define B_ 8
#define N_ 2048
#define F_ 64
#define FH_ 64
#define H_ 4
#define C_ (H_*FH_)
#define CHUNK 64
#define NCHUNK (N_/CHUNK)
#define LOG2E 1.44269504088896340736f

typedef short short8 __attribute__((ext_vector_type(8)));   // 8 bf16 raw bits (4 VGPRs)
typedef float f32x4 __attribute__((ext_vector_type(4)));

// float -> bf16 raw bits (RNE)
__device__ __forceinline__ short f2bf(float f) {
    __hip_bfloat16 h = __float2bfloat16(f);
    return __builtin_bit_cast(short, h);
}

// async global->LDS DMA
__device__ __forceinline__ void async16(void* l, const void* g) {
    __builtin_amdgcn_global_load_lds((const __attribute__((address_space(1))) unsigned int*)g,
                                     (__attribute__((address_space(3))) unsigned int*)l, 16, 0, 0);
}

// ---------------- KF: fused [k1 feats+scores | kp mask-pack] (unchanged) ----------------
// Blocks [0,1024): k1 (featsT + ss/sn). Blocks [1024,5120): kp (A -> 1-bit mask).
// Fusing overlaps the ~20 us HBM-bound A read with the k1 MFMA work.
__global__ __launch_bounds__(256) void kf(const float* __restrict__ A,
                                          const float* __restrict__ X,
                                          const float* __restrict__ W,
                                          const float* __restrict__ a_self,
                                          const float* __restrict__ a_neigh,
                                          unsigned long long* __restrict__ Amask,
                                          __hip_bfloat16* __restrict__ featsT,
                                          float* __restrict__ ss,
                                          float* __restrict__ sn) {
    __shared__ float a_lds[2][FH_];
    __shared__ __hip_bfloat16 cw_lds[FH_ * 72];    // W^T (bf16) during MFMA, then C
    const int bx = blockIdx.x;
    const int tid = threadIdx.x;
    const int wave = tid >> 6, lane = tid & 63;

    if (bx >= 1024) {
        // ---------------- kp part ----------------
        const int R = (bx - 1024) * 4 + wave;      // global row 0..16383 (= b*N + i)
        const float* arow = A + (size_t)R * N_;
        unsigned long long* mrow = Amask + (size_t)R * (N_ / 64);
#pragma unroll
        for (int i = 0; i < 8; ++i) {              // 8 x 256 cols
            float a0 = arow[i * 256 + lane];
            float a1 = arow[i * 256 + 64 + lane];
            float a2 = arow[i * 256 + 128 + lane];
            float a3 = arow[i * 256 + 192 + lane];
            unsigned long long m0 = __ballot(a0 != 0.0f);
            unsigned long long m1 = __ballot(a1 != 0.0f);
            unsigned long long m2 = __ballot(a2 != 0.0f);
            unsigned long long m3 = __ballot(a3 != 0.0f);
            if (lane == 0) {
                mrow[i * 4 + 0] = m0; mrow[i * 4 + 1] = m1;
                mrow[i * 4 + 2] = m2; mrow[i * 4 + 3] = m3;
            }
        }
        return;
    }

    // ---------------- k1 part ----------------
    const int nb = bx & 31, h = (bx >> 5) & 3, b = bx >> 7;

    if (tid < 64)       a_lds[0][tid] = a_self[h * FH_ + tid];
    else if (tid < 128) a_lds[1][tid - 64] = a_neigh[h * FH_ + tid - 64];
    {   // stage W[h] transposed to bf16: cw_lds[o*72+f] = bf16(W[h][f][o])
        int f = tid >> 2, o0 = (tid & 3) * 16;
        const float* wsrc = W + ((size_t)(h * F_ + f)) * FH_ + o0;
#pragma unroll
        for (int k = 0; k < 16; ++k)
            cw_lds[(o0 + k) * 72 + f] = __float2bfloat16(wsrc[k]);
    }
    __syncthreads();

    const int m = lane & 15, q = lane >> 4;
    const int nl = wave * 16 + m;               // local column 0..63
    const int n = nb * 64 + nl;                 // B-frag column (node index)
    f32x4 acc[4] = {};
#pragma unroll
    for (int ks = 0; ks < 2; ++ks) {            // K = F = 64, two steps of 32
        const float* xp = X + ((size_t)(b * N_ + n)) * F_ + ks * 32 + q * 8;
        float4 x0 = *(const float4*)xp;
        float4 x1 = *(const float4*)(xp + 4);
        short8 bfrag;
        bfrag[0] = f2bf(x0.x); bfrag[1] = f2bf(x0.y);
        bfrag[2] = f2bf(x0.z); bfrag[3] = f2bf(x0.w);
        bfrag[4] = f2bf(x1.x); bfrag[5] = f2bf(x1.y);
        bfrag[6] = f2bf(x1.z); bfrag[7] = f2bf(x1.w);
#pragma unroll
        for (int ot = 0; ot < 4; ++ot) {
            short8 afrag = *(const short8*)(cw_lds + (ot * 16 + m) * 72 + ks * 32 + q * 8);
            acc[ot] = __builtin_amdgcn_mfma_f32_16x16x32_bf16(afrag, bfrag, acc[ot], 0, 0, 0);
        }
    }
    __syncthreads();    // all W reads done before C overwrites the buffer
    float ssv = 0.f, snv = 0.f;
#pragma unroll
    for (int ot = 0; ot < 4; ++ot) {
#pragma unroll
        for (int r = 0; r < 4; ++r) {
            int orow = ot * 16 + q * 4 + r;     // C: row=(lane>>4)*4+r, col=lane&15
            float v = acc[ot][r];
            cw_lds[orow * 72 + nl] = __float2bfloat16(v);
            ssv += v * a_lds[0][orow];
            snv += v * a_lds[1][orow];
        }
    }
    ssv += __shfl_xor(ssv, 16); ssv += __shfl_xor(ssv, 32);
    snv += __shfl_xor(snv, 16); snv += __shfl_xor(snv, 32);
    __syncthreads();
    {   // coalesced featsT store: thread t -> feature o = t>>2, 16-col chunk (t&3)
        int o = tid >> 2, c = (tid & 3) * 16;
        const __hip_bfloat16* src = cw_lds + o * 72 + c;
        __hip_bfloat16* dst = featsT + ((size_t)(b * H_ + h) * FH_ + o) * N_ + nb * 64 + c;
        *(uint4*)dst       = *(const uint4*)src;
        *(uint4*)(dst + 8) = *(const uint4*)(src + 8);
    }
    if (lane < 16) {
        size_t idx = ((size_t)(b * H_ + h)) * N_ + n;
        ss[idx] = ssv * LOG2E;
        sn[idx] = snv * LOG2E;
    }
}

// ---------------- K3: DMA-pipelined fused softmax+PV, 128-row blocks (R21) ----------------
// Per-wave structure = R15 verbatim (best verified 249.5; survived 6 structural
// attacks). ONE change: blocks widened to 512 threads / 8 waves / 128 rows.
// Each wave is an exact R15 wave (16 rows, chains A/B, same buildP/barriers/
// epilogue, per-thread VGPR unchanged) -- but only 16 blocks now share each
// (b,h) featsT panel instead of 32: fv DMA bytes 256 MB -> 128 MB, e-table
// builds and barrier-drain events halve. Occupancy preserved: grid 512 =
// 2 blocks/CU x 8 waves = 16 waves/CU (VGPR-capped 4 waves/SIMD, same as R15).
// LDS 32 KB x 2 blocks = 64 KB. Numerics bit-identical to R12.
__global__ __launch_bounds__(512, 4) void k3_attn(const unsigned int* __restrict__ Amask,
                                                  const __hip_bfloat16* __restrict__ featsT,
                                                  const float* __restrict__ ss,
                                                  const float* __restrict__ sn,
                                                  const float* __restrict__ bias,
                                                  float* __restrict__ out) {
    __shared__ __hip_bfloat16 fv_lds[2][64 * CHUNK];   // 2 x 8 KB, swizzled
    __shared__ float e1_lds[N_];                       // 8 KB: 2^sn_j
    __shared__ float e2_lds[N_];                       // 8 KB: 2^(0.2 sn_j)

    const int tile = blockIdx.x, h = blockIdx.y, b = blockIdx.z;   // tile in [0,16)
    const int tid = threadIdx.x, wave = tid >> 6, lane = tid & 63; // wave in [0,8)
    const int m = lane & 15, q = lane >> 4;
    const int rowtile = tile * 128;
    const int wrow = rowtile + wave * 16;              // this wave's 16-row group

    {   // e-tables: 512 float4 slots, one per thread
        const float4* snrow = (const float4*)(sn + ((size_t)(b * H_ + h)) * N_);
        float4* e1v = (float4*)e1_lds;
        float4* e2v = (float4*)e2_lds;
        int idx = tid;
        float4 v = snrow[idx];
        float4 u1, u2;
        u1.x = exp2f(v.x); u1.y = exp2f(v.y); u1.z = exp2f(v.z); u1.w = exp2f(v.w);
        u2.x = exp2f(0.2f * v.x); u2.y = exp2f(0.2f * v.y);
        u2.z = exp2f(0.2f * v.z); u2.w = exp2f(0.2f * v.w);
        e1v[idx] = u1; e2v[idx] = u2;
    }
    const float ssi = ss[((size_t)(b * H_ + h)) * N_ + wrow + m];
    const float e1i = exp2f(ssi), e2i = exp2f(0.2f * ssi);

    const __hip_bfloat16* fhead = featsT + ((size_t)(b * H_ + h)) * FH_ * N_;
    // per-thread mask row pointer: row = wrow + m, 2 dwords per chunk
    const unsigned int* mrow = Amask + ((size_t)(b * N_) + wrow + m) * (N_ / 32);

    // stage fv chunk c into buffer bufi: 512 16B-units, exactly one per thread
    // (wave-uniform LDS base + lane*16B per HW contract)
    auto stage = [&](int c, int bufi) {
        const int cb = c * CHUNK;
        int base_unit = wave * 64;
        int unit = base_unit + lane;
        int o = unit >> 3, v = unit & 7;
        int u = v ^ (o & 7);                    // XOR swizzle (compute-side conflict-free)
        async16(&fv_lds[bufi][base_unit * 8], fhead + (size_t)o * N_ + cb + u * 8);
    };

    // build P (pA, pB) for chunk c from static e-tables + mask registers
    auto buildP = [&](int c, unsigned int mA, unsigned int mB, short8& pA, short8& pB) {
        const int cg = c * CHUNK;
        float4 eA10 = *(const float4*)(e1_lds + cg + q * 8);
        float4 eA11 = *(const float4*)(e1_lds + cg + q * 8 + 4);
        float4 eB10 = *(const float4*)(e1_lds + cg + 32 + q * 8);
        float4 eB11 = *(const float4*)(e1_lds + cg + 32 + q * 8 + 4);
        float4 eA20 = *(const float4*)(e2_lds + cg + q * 8);
        float4 eA21 = *(const float4*)(e2_lds + cg + q * 8 + 4);
        float4 eB20 = *(const float4*)(e2_lds + cg + 32 + q * 8);
        float4 eB21 = *(const float4*)(e2_lds + cg + 32 + q * 8 + 4);
        float e1A[8] = {eA10.x, eA10.y, eA10.z, eA10.w, eA11.x, eA11.y, eA11.z, eA11.w};
        float e1B[8] = {eB10.x, eB10.y, eB10.z, eB10.w, eB11.x, eB11.y, eB11.z, eB11.w};
        float e2A[8] = {eA20.x, eA20.y, eA20.z, eA20.w, eA21.x, eA21.y, eA21.z, eA21.w};
        float e2B[8] = {eB20.x, eB20.y, eB20.z, eB20.w, eB21.x, eB21.y, eB21.z, eB21.w};
#pragma unroll
        for (int t = 0; t < 8; ++t) {
            // exp2(leaky(si+sj)) = max(e1i*e1j, e2i*e2j); adjacency via bit test
            float vA = fmaxf(e1i * e1A[t], e2i * e2A[t]);
            float vB = fmaxf(e1i * e1B[t], e2i * e2B[t]);
            const int bit = q * 8 + t;
            pA[t] = (mA >> bit) & 1 ? f2bf(vA) : (short)0;
            pB[t] = (mB >> bit) & 1 ? f2bf(vB) : (short)0;
        }
    };

    // early mask loads (latency hidden under e-table exp2 work)
    uint2 mk_use = *(const uint2*)(mrow + 0);   // chunk 0
    uint2 mk_a   = *(const uint2*)(mrow + 2);   // chunk 1

    stage(0, 0);
    __syncthreads();    // drains DMA (vmcnt -> masks also landed) + e-table LDS writes

    f32x4 acc[2][4] = {};       // [chain][ct]
    f32x4 accl[2] = {};
    short8 ones;
#pragma unroll
    for (int t = 0; t < 8; ++t) ones[t] = (short)0x3F80;   // bf16 1.0

    short8 pA, pB;
    buildP(0, mk_use.x, mk_use.y, pA, pB);

    for (int c = 0; c < NCHUNK; ++c) {
        const int cur = c & 1;
        if (c + 1 < NCHUNK) stage(c + 1, cur ^ 1);
        uint2 mk_b = mk_a;
        if (c + 2 < NCHUNK) mk_b = *(const uint2*)(mrow + (c + 2) * 2);

        // fv fragments: chain A = col-units 0..3 (uA=q), chain B = units 4..7
        short8 fA[4], fB[4];
#pragma unroll
        for (int ct = 0; ct < 4; ++ct) {
            int o = ct * 16 + m;
            fA[ct] = *(const short8*)(fv_lds[cur] + ((o << 3) + (q ^ (o & 7))) * 8);
            fB[ct] = *(const short8*)(fv_lds[cur] + ((o << 3) + ((4 + q) ^ (o & 7))) * 8);
        }
#pragma unroll
        for (int ct = 0; ct < 4; ++ct) {
            acc[0][ct] = __builtin_amdgcn_mfma_f32_16x16x32_bf16(pA, fA[ct], acc[0][ct], 0, 0, 0);
            acc[1][ct] = __builtin_amdgcn_mfma_f32_16x16x32_bf16(pB, fB[ct], acc[1][ct], 0, 0, 0);
        }
        accl[0] = __builtin_amdgcn_mfma_f32_16x16x32_bf16(pA, ones, accl[0], 0, 0, 0);
        accl[1] = __builtin_amdgcn_mfma_f32_16x16x32_bf16(pB, ones, accl[1], 0, 0, 0);

        // build P for next chunk while this chunk's DMA is in flight (in-place:
        // MFMAs above have consumed the old pA/pB)
        if (c + 1 < NCHUNK) buildP(c + 1, mk_a.x, mk_a.y, pA, pB);
        mk_a = mk_b;

        __syncthreads();    // drain next-chunk DMA; release cur buffer
    }

    float bc[4];
#pragma unroll
    for (int ct = 0; ct < 4; ++ct) bc[ct] = bias[h * FH_ + ct * 16 + m];

#pragma unroll
    for (int r = 0; r < 4; ++r) {
        float inv = 1.0f / (accl[0][r] + accl[1][r]);   // row sum (all cols identical)
        int gr = wrow + q * 4 + r;
#pragma unroll
        for (int ct = 0; ct < 4; ++ct) {
            float v = (acc[0][ct][r] + acc[1][ct][r]) * inv + bc[ct];
            out[((size_t)(b * N_) + gr) * C_ + h * FH_ + ct * 16 + m] = fmaxf(v, 0.0f);
        }
    }
}

extern "C" void kernel_launch(void* const* d_in, const int* in_sizes, int n_in,
                              void* d_out, int out_size, void* d_ws, size_t ws_size,
                              hipStream_t stream) {
    const float* X       = (const float*)d_in[0];
    const float* A       = (const float*)d_in[1];
    const float* W       = (const float*)d_in[2];
    const float* bias    = (const float*)d_in[3];
    const float* a_self  = (const float*)d_in[4];
    const float* a_neigh = (const float*)d_in[5];
    float* out = (float*)d_out;   // reference output dtype is float32

    char* ws = (char*)d_ws;
    __hip_bfloat16* featsT = (__hip_bfloat16*)(ws);             // 8 MB   [B][H][FH][N]
    float* ss              = (float*)(ws + 8421376);            // 256 KB [B][H][N]
    float* sn              = (float*)(ws + 8683520);            // 256 KB [B][H][N]
    unsigned long long* Am = (unsigned long long*)(ws + 8945664); // 4 MB bitmask

    kf      <<<5120, 256, 0, stream>>>(A, X, W, a_self, a_neigh, Am, featsT, ss, sn);
    k3_attn <<<dim3(N_ / 128, H_, B_), 512, 0, stream>>>((const unsigned int*)Am, featsT, ss, sn, bias, out);
}